// Round 14
// baseline (98.771 us; speedup 1.0000x reference)
//
#include <hip/hip_runtime.h>

#define B_ 2
#define NCAM_ 6
#define C_ 256
#define HF_ 64
#define WF_ 176
#define NX_ 200
#define NY_ 200
#define NZ_ 4
#define V_ (NX_*NY_*NZ_)      /* 160000 */
#define HW_ (HF_*WF_)         /* 11264 */
#define OUTC_ 80
#define NPOS_ (NX_*NY_)       /* 40000 */
#define NBLK3_ 1250           /* k3 blocks = 625*2 */

typedef unsigned short u16;
typedef unsigned int   u32;
typedef __attribute__((ext_vector_type(8))) short bf16x8;
typedef __attribute__((ext_vector_type(4))) float f32x4;
typedef __attribute__((ext_vector_type(2))) unsigned int u32x2;
typedef __attribute__((ext_vector_type(4))) unsigned int u32x4;

/* workspace layout (float offsets) */
#define WS_PROJ 0            /* 144: [b][n][3][4] */
#define WS_IMGT 144          /* 24:  [b][n][2] */
#define WS_SCALE 256         /* 80 */
#define WS_SHIFT 336         /* 80 */
#define WS_WB   2048         /* u32[8][5][64][4] = 10240 u32 */
#define WS_PF   336384       /* u16[12*11264*80] = 5406720 floats */
#define WS_PART 5743104      /* 2*80*1250 = 200000 floats */
#define WS_YBF  5943104      /* u16[2*80*40000] = 3200000 floats */

__device__ __forceinline__ u16 f2bf(float x) {
    u32 u = __float_as_uint(x);
    u32 r = (u + 0x7fffu + ((u >> 16) & 1u)) >> 16;   // RNE
    return (u16)r;
}
__device__ __forceinline__ float bf2f(u16 v) {
    return __uint_as_float(((u32)v) << 16);
}

// ---------------------------------------------------------------- K0: prep
__global__ void k0_prep(const float* __restrict__ l2i,
                        const float* __restrict__ img_aug,
                        const float* __restrict__ conv_w,
                        float* __restrict__ ws)
{
    int t = threadIdx.x;
    if (t < B_*NCAM_*12) {
        int bn = t / 12;
        int e  = t % 12;
        int i = e >> 2, j = e & 3;
        const float* A = img_aug + bn*16;
        const float* L = l2i + bn*16;
        float acc = 0.f;
        #pragma unroll
        for (int k = 0; k < 4; ++k) {
            float a = (k < 3) ? A[i*4 + k] : 0.f;   // img_r: column 3 zeroed
            acc = fmaf(a, L[k*4 + j], acc);
        }
        ws[WS_PROJ + t] = acc;
    }
    if (t >= 192 && t < 192 + B_*NCAM_*2) {
        int s = t - 192;
        int bn = s >> 1, i = s & 1;
        ws[WS_IMGT + s] = img_aug[bn*16 + i*4 + 3];
    }
    u32* wbp = (u32*)(ws + WS_WB);
    for (int i = t; i < 8*5*64*4; i += 256) {
        int ks = i / 1280;
        int r  = i - ks*1280;
        int u  = r >> 8;
        int r2 = r & 255;
        int l  = r2 >> 2;
        int j  = r2 & 3;
        int la = l & 15, hi = l >> 4;
        int o  = u*16 + la;
        int cb = ks*32 + ((j >> 1) << 4) + hi*4 + ((j & 1) << 1);
        wbp[i] = (u32)f2bf(conv_w[o*C_ + cb]) | ((u32)f2bf(conv_w[o*C_ + cb + 1]) << 16);
    }
}

// ---------------------------- K2: pf[bn][hw][o] = W @ feat  (bf16 MFMA)
// 64-hw tile, 16 KiB dbuf, 8 blocks/CU, XCD-aware hw-block swizzle,
// NT feat reads (read exactly once -> don't pollute L2),
// dense LDS-repacked epilogue (one contiguous 10,240-B stream per block).
__global__ __launch_bounds__(256, 8) void k2_mfma(const float* __restrict__ feat,
                                                  const u32* __restrict__ wbp,
                                                  u16* __restrict__ pf)
{
    __shared__ float lds[2][32][64];   // 16 KiB
    const int bn  = blockIdx.y;
    const int x   = blockIdx.x;
    const int xsw = (x & 7)*22 + (x >> 3);   // bijective over 176
    const int hw0 = xsw*64;
    const int t   = threadIdx.x;
    const int wv  = t >> 6;        // wave 0..3
    const int l   = t & 63;
    const int la  = l & 15;
    const int hi  = l >> 4;

    const float* fb = feat + (size_t)bn*C_*HW_ + hw0;

#define STAGE(buf, c0) do { \
    _Pragma("unroll") for (int i_ = 0; i_ < 2; ++i_) { \
        int r0_ = i_*16 + wv*4; \
        const float* src_ = fb + (size_t)((c0) + r0_ + (l >> 4))*HW_ + (l & 15)*4; \
        __builtin_amdgcn_global_load_lds( \
            (const __attribute__((address_space(1))) unsigned int*)src_, \
            (__attribute__((address_space(3))) unsigned int*)&lds[buf][r0_][0], \
            16, 0, 2 /* NT */); \
    } \
} while (0)

    f32x4 acc[5] = {};
    STAGE(0, 0);
    for (int ks = 0; ks < 8; ++ks) {
        const int cur = ks & 1;
        __syncthreads();                    // staged data for 'cur' visible
        if (ks < 7) STAGE(cur ^ 1, (ks+1)*32);
        // ---- B-fragment from LDS
        const int hwl = wv*16 + la;
        union { u32 u[4]; bf16x8 v; } Bf;
        #pragma unroll
        for (int j = 0; j < 4; ++j) {
            const int cb = ((j >> 1) << 4) + hi*4 + ((j & 1) << 1);
            Bf.u[j] = (u32)f2bf(lds[cur][cb][hwl]) |
                      ((u32)f2bf(lds[cur][cb+1][hwl]) << 16);
        }
        // ---- A-fragments interleaved with MFMA (low VGPR)
        #pragma unroll
        for (int u = 0; u < 5; ++u) {
            union { u32x4 q; bf16x8 v; } A;
            A.q = *(const u32x4*)&wbp[((ks*5 + u)*64 + l)*4];
            acc[u] = __builtin_amdgcn_mfma_f32_16x16x32_bf16(A.v, Bf.v, acc[u], 0, 0, 0);
        }
    }
#undef STAGE

    // ---- dense epilogue: repack via LDS, one contiguous 10,240-B stream
    __syncthreads();                       // all LDS reads of K-loop done
    u16* yt = (u16*)lds;                   // [64 hw][80 o] bf16 = 10,240 B
    {
        const int hwl = wv*16 + la;
        #pragma unroll
        for (int u = 0; u < 5; ++u) {
            f32x4 a = acc[u];
            u32 p0 = (u32)f2bf(a.x) | ((u32)f2bf(a.y) << 16);
            u32 p1 = (u32)f2bf(a.z) | ((u32)f2bf(a.w) << 16);
            u32x2 pk; pk.x = p0; pk.y = p1;
            *(u32x2*)&yt[hwl*80 + u*16 + hi*4] = pk;
        }
    }
    __syncthreads();
    const u32x4* src128 = (const u32x4*)yt;
    u32x4* dst128 = (u32x4*)(pf + (size_t)(bn*HW_ + hw0)*80);
    #pragma unroll
    for (int i = 0; i < 3; ++i) {
        int k = t + i*256;
        if (k < 640) dst128[k] = src128[k];   // 640 x 16 B = 10,240 B
    }
}

// --------------- K3: inline projection + gather + bias -> ybf(bf16), + stats
// 640 threads (10 waves): doubles gather MLP, halves the serial i-loop.
// XCD-swizzled (bijective, nwg=1250=8*156+2) for pf L2 locality.
__global__ __launch_bounds__(640) void k3_gather(const float* __restrict__ ws,
                                                 const float* __restrict__ lidar_aug,
                                                 const float* __restrict__ points,
                                                 const u16* __restrict__ pf,
                                                 const float* __restrict__ conv_b,
                                                 u16* __restrict__ ybf,
                                                 float* __restrict__ part)
{
    __shared__ int   idx_s[256];
    __shared__ float w_s[256];
    __shared__ float y_s[OUTC_][65];
    const int wlin = blockIdx.y*625 + blockIdx.x;
    const int q = NBLK3_ >> 3, r = NBLK3_ & 7;      // 156, 2
    const int xcd = wlin & 7, iw = wlin >> 3;
    const int wg = (xcd < r) ? xcd*(q+1) + iw : r*(q+1) + (xcd - r)*q + iw;
    const int b = wg / 625;
    const int tile = wg - b*625;
    int t = threadIdx.x;
    if (t < 256) {
        // ---- points load (issue first)
        int izl = t >> 6, p = t & 63;
        w_s[izl*64 + p] = points[b*V_ + izl*NPOS_ + tile*64 + p];
        // ---- inline voxel -> camera-index projection
        int v = tile*256 + t;
        int ixy = v >> 2;
        int iz  = v & 3;
        int ix = ixy / NY_;
        int iy = ixy - ix*NY_;
        float x = ix*0.5f - 50.f;
        float y = iy*0.5f - 50.f;
        float z = iz*1.5f - 4.f;
        const float* la = lidar_aug + b*16;
        float gx = x - la[3], gy = y - la[7], gz = z - la[11];
        float px = fmaf(la[8],  gz, fmaf(la[4], gy, fmaf(la[0], gx, 0.f)));
        float py = fmaf(la[9],  gz, fmaf(la[5], gy, fmaf(la[1], gx, 0.f)));
        float pz = fmaf(la[10], gz, fmaf(la[6], gy, fmaf(la[2], gx, 0.f)));
        int best = -1;
        #pragma unroll
        for (int n = 0; n < NCAM_; ++n) {
            const float* P = ws + WS_PROJ + (b*NCAM_ + n)*12;
            float t0 = fmaf(P[3], 1.f, fmaf(P[2],  pz, fmaf(P[1], py, fmaf(P[0], px, 0.f))));
            float t1 = fmaf(P[7], 1.f, fmaf(P[6],  pz, fmaf(P[5], py, fmaf(P[4], px, 0.f))));
            float t2 = fmaf(P[11],1.f, fmaf(P[10], pz, fmaf(P[9], py, fmaf(P[8], px, 0.f))));
            float u = t0/t2 + ws[WS_IMGT + (b*NCAM_+n)*2 + 0];
            float w = t1/t2 + ws[WS_IMGT + (b*NCAM_+n)*2 + 1];
            int uf = (int)rintf(u*0.25f);
            int vf = (int)rintf(w*0.25f);
            if (uf >= 0 && vf >= 0 && uf < WF_ && vf < HF_ && t2 > 0.f)
                best = n*HW_ + vf*WF_ + uf;
        }
        idx_s[t] = best;
    }
    __syncthreads();
    int o  = t % 80;
    int pg = t / 80;             // 0..7
    float bias = conv_b[o];
    const u16* pfb = pf + (size_t)b*(NCAM_*HW_)*80;
    for (int i = 0; i < 8; ++i) {
        int p = pg*8 + i;
        float acc = bias;
        #pragma unroll
        for (int iz = 0; iz < 4; ++iz) {
            int g = idx_s[p*4 + iz];
            if (g >= 0) acc = fmaf(w_s[iz*64 + p], bf2f(pfb[(size_t)g*80 + o]), acc);
        }
        y_s[o][p] = acc;
    }
    __syncthreads();
    // ---- coalesced bf16 y write (pairs packed to u32)
    u16* yb = ybf + (size_t)b*OUTC_*NPOS_ + tile*64;
    for (int lq = t; lq < OUTC_*32; lq += 640) {
        int oo = lq >> 5, p2 = (lq & 31) << 1;
        u32 pk = (u32)f2bf(y_s[oo][p2]) | ((u32)f2bf(y_s[oo][p2+1]) << 16);
        *(u32*)&yb[(size_t)oo*NPOS_ + p2] = pk;
    }
    // ---- per-block BN partial sums (80 ch x 1250 blocks), from f32 y_s
    int oo = t >> 3, qq = t & 7;          // 640 = 80 x 8
    float s1 = 0.f, s2 = 0.f;
    #pragma unroll
    for (int i = 0; i < 8; ++i) {
        float v = y_s[oo][qq*8 + i];
        s1 += v; s2 += v*v;
    }
    s1 += __shfl_xor(s1, 1, 8); s2 += __shfl_xor(s2, 1, 8);
    s1 += __shfl_xor(s1, 2, 8); s2 += __shfl_xor(s2, 2, 8);
    s1 += __shfl_xor(s1, 4, 8); s2 += __shfl_xor(s2, 4, 8);
    if (qq == 0) {
        int bb = b*625 + tile;
        part[oo*NBLK3_ + bb] = s1;
        part[OUTC_*NBLK3_ + oo*NBLK3_ + bb] = s2;
    }
}

// ---------------------------------- K4: reduce partials -> scale/shift
__global__ __launch_bounds__(256) void k4_final(const float* __restrict__ part,
                                                const float* __restrict__ gamma,
                                                const float* __restrict__ beta,
                                                float* __restrict__ ws)
{
    int o = blockIdx.x;
    int t = threadIdx.x;
    float s1 = 0.f, s2 = 0.f;
    for (int j = t; j < NBLK3_; j += 256) {
        s1 += part[o*NBLK3_ + j];
        s2 += part[OUTC_*NBLK3_ + o*NBLK3_ + j];
    }
    __shared__ float r1[256], r2[256];
    r1[t] = s1; r2[t] = s2;
    __syncthreads();
    for (int s = 128; s > 0; s >>= 1) {
        if (t < s) { r1[t] += r1[t+s]; r2[t] += r2[t+s]; }
        __syncthreads();
    }
    if (t == 0) {
        const float invN = 1.f/(float)(B_*NPOS_);
        float mean = r1[0]*invN;
        float var  = r2[0]*invN - mean*mean;
        float inv  = rsqrtf(var + 1e-5f);
        float sc   = gamma[o]*inv;
        ws[WS_SCALE + o] = sc;
        ws[WS_SHIFT + o] = beta[o] - mean*sc;
    }
}

// ------------------------------- K5: affine + ReLU, bf16 y -> f32 out (NT)
__global__ __launch_bounds__(256) void k5_norm(const u32* __restrict__ ybf,
                                               const float* __restrict__ ws,
                                               float* __restrict__ out)
{
    int gid = blockIdx.x*256 + threadIdx.x;
    int f = gid*8;
    if (f >= B_*OUTC_*NPOS_) return;
    int o = (f / NPOS_) % OUTC_;     // 40000 % 8 == 0 -> whole group shares o
    float sc = ws[WS_SCALE + o], sh = ws[WS_SHIFT + o];
    u32x4 v = *(const u32x4*)&ybf[gid*4];
    f32x4 r0, r1;
    r0.x = fmaxf(fmaf(bf2f((u16)(v.x & 0xffff)), sc, sh), 0.f);
    r0.y = fmaxf(fmaf(bf2f((u16)(v.x >> 16)),    sc, sh), 0.f);
    r0.z = fmaxf(fmaf(bf2f((u16)(v.y & 0xffff)), sc, sh), 0.f);
    r0.w = fmaxf(fmaf(bf2f((u16)(v.y >> 16)),    sc, sh), 0.f);
    r1.x = fmaxf(fmaf(bf2f((u16)(v.z & 0xffff)), sc, sh), 0.f);
    r1.y = fmaxf(fmaf(bf2f((u16)(v.z >> 16)),    sc, sh), 0.f);
    r1.z = fmaxf(fmaf(bf2f((u16)(v.w & 0xffff)), sc, sh), 0.f);
    r1.w = fmaxf(fmaf(bf2f((u16)(v.w >> 16)),    sc, sh), 0.f);
    __builtin_nontemporal_store(r0, (f32x4*)&out[f]);
    __builtin_nontemporal_store(r1, (f32x4*)&out[f + 4]);
}

extern "C" void kernel_launch(void* const* d_in, const int* in_sizes, int n_in,
                              void* d_out, int out_size, void* d_ws, size_t ws_size,
                              hipStream_t stream) {
    (void)in_sizes; (void)n_in; (void)out_size; (void)ws_size;
    const float* feat      = (const float*)d_in[0];
    const float* points    = (const float*)d_in[1];
    const float* l2i       = (const float*)d_in[2];
    const float* img_aug   = (const float*)d_in[3];
    const float* lidar_aug = (const float*)d_in[4];
    const float* conv_w    = (const float*)d_in[5];
    const float* conv_b    = (const float*)d_in[6];
    const float* gamma     = (const float*)d_in[7];
    const float* beta      = (const float*)d_in[8];
    float* out = (float*)d_out;
    float* wsf = (float*)d_ws;
    u32*   wbp = (u32*)(wsf + WS_WB);
    u16*   pf  = (u16*)(wsf + WS_PF);
    float* part = wsf + WS_PART;
    u16*   ybf = (u16*)(wsf + WS_YBF);

    hipLaunchKernelGGL(k0_prep, dim3(1), dim3(256), 0, stream, l2i, img_aug, conv_w, wsf);
    hipLaunchKernelGGL(k2_mfma, dim3(HW_/64, B_*NCAM_), dim3(256), 0, stream, feat, wbp, pf);
    hipLaunchKernelGGL(k3_gather, dim3(625, B_), dim3(640), 0, stream, wsf, lidar_aug, points, pf, conv_b, ybf, part);
    hipLaunchKernelGGL(k4_final, dim3(OUTC_), dim3(256), 0, stream, part, gamma, beta, wsf);
    hipLaunchKernelGGL(k5_norm, dim3((B_*OUTC_*NPOS_/8)/256 + 1, 1), dim3(256), 0, stream, (const u32*)ybf, wsf, out);
}

// Round 15
// 88.904 us; speedup vs baseline: 1.1110x; 1.1110x over previous
//
#include <hip/hip_runtime.h>

#define B_ 2
#define NCAM_ 6
#define C_ 256
#define HF_ 64
#define WF_ 176
#define NX_ 200
#define NY_ 200
#define NZ_ 4
#define V_ (NX_*NY_*NZ_)      /* 160000 */
#define HW_ (HF_*WF_)         /* 11264 */
#define OUTC_ 80
#define NPOS_ (NX_*NY_)       /* 40000 */
#define NBLK3_ 1250           /* k3 blocks = 625*2 */

typedef unsigned short u16;
typedef unsigned int   u32;
typedef __attribute__((ext_vector_type(8))) short bf16x8;
typedef __attribute__((ext_vector_type(4))) float f32x4;
typedef __attribute__((ext_vector_type(2))) unsigned int u32x2;
typedef __attribute__((ext_vector_type(4))) unsigned int u32x4;

/* workspace layout (float offsets) */
#define WS_PROJ 0            /* 144: [b][n][3][4] */
#define WS_IMGT 144          /* 24:  [b][n][2] */
#define WS_SCALE 256         /* 80 */
#define WS_SHIFT 336         /* 80 */
#define WS_WB   2048         /* u32[8][5][64][4] = 10240 u32 */
#define WS_PF   336384       /* u16[12*11264*80] = 5406720 floats */
#define WS_PART 5743104      /* 2*80*1250 = 200000 floats */
#define WS_YBF  5943104      /* u16[2*80*40000] = 3200000 floats */

__device__ __forceinline__ u16 f2bf(float x) {
    u32 u = __float_as_uint(x);
    u32 r = (u + 0x7fffu + ((u >> 16) & 1u)) >> 16;   // RNE
    return (u16)r;
}
__device__ __forceinline__ float bf2f(u16 v) {
    return __uint_as_float(((u32)v) << 16);
}

// ---------------------------------------------------------------- K0: prep
__global__ void k0_prep(const float* __restrict__ l2i,
                        const float* __restrict__ img_aug,
                        const float* __restrict__ conv_w,
                        float* __restrict__ ws)
{
    int t = threadIdx.x;
    if (t < B_*NCAM_*12) {
        int bn = t / 12;
        int e  = t % 12;
        int i = e >> 2, j = e & 3;
        const float* A = img_aug + bn*16;
        const float* L = l2i + bn*16;
        float acc = 0.f;
        #pragma unroll
        for (int k = 0; k < 4; ++k) {
            float a = (k < 3) ? A[i*4 + k] : 0.f;   // img_r: column 3 zeroed
            acc = fmaf(a, L[k*4 + j], acc);
        }
        ws[WS_PROJ + t] = acc;
    }
    if (t >= 192 && t < 192 + B_*NCAM_*2) {
        int s = t - 192;
        int bn = s >> 1, i = s & 1;
        ws[WS_IMGT + s] = img_aug[bn*16 + i*4 + 3];
    }
    u32* wbp = (u32*)(ws + WS_WB);
    for (int i = t; i < 8*5*64*4; i += 256) {
        int ks = i / 1280;
        int r  = i - ks*1280;
        int u  = r >> 8;
        int r2 = r & 255;
        int l  = r2 >> 2;
        int j  = r2 & 3;
        int la = l & 15, hi = l >> 4;
        int o  = u*16 + la;
        int cb = ks*32 + ((j >> 1) << 4) + hi*4 + ((j & 1) << 1);
        wbp[i] = (u32)f2bf(conv_w[o*C_ + cb]) | ((u32)f2bf(conv_w[o*C_ + cb + 1]) << 16);
    }
}

// ---------------------------- K2: pf[bn][hw][o] = W @ feat  (bf16 MFMA)
// 64-hw tile, 16 KiB dbuf, 8 blocks/CU, XCD-aware hw-block swizzle,
// dense LDS-repacked epilogue. aux=0 (default caching) — R14's aux=2
// "NT" probe regressed 18 us; reverted.
__global__ __launch_bounds__(256, 8) void k2_mfma(const float* __restrict__ feat,
                                                  const u32* __restrict__ wbp,
                                                  u16* __restrict__ pf)
{
    __shared__ float lds[2][32][64];   // 16 KiB
    const int bn  = blockIdx.y;
    const int x   = blockIdx.x;
    const int xsw = (x & 7)*22 + (x >> 3);   // bijective over 176
    const int hw0 = xsw*64;
    const int t   = threadIdx.x;
    const int wv  = t >> 6;        // wave 0..3
    const int l   = t & 63;
    const int la  = l & 15;
    const int hi  = l >> 4;

    const float* fb = feat + (size_t)bn*C_*HW_ + hw0;

#define STAGE(buf, c0) do { \
    _Pragma("unroll") for (int i_ = 0; i_ < 2; ++i_) { \
        int r0_ = i_*16 + wv*4; \
        const float* src_ = fb + (size_t)((c0) + r0_ + (l >> 4))*HW_ + (l & 15)*4; \
        __builtin_amdgcn_global_load_lds( \
            (const __attribute__((address_space(1))) unsigned int*)src_, \
            (__attribute__((address_space(3))) unsigned int*)&lds[buf][r0_][0], \
            16, 0, 0); \
    } \
} while (0)

    f32x4 acc[5] = {};
    STAGE(0, 0);
    for (int ks = 0; ks < 8; ++ks) {
        const int cur = ks & 1;
        __syncthreads();                    // staged data for 'cur' visible
        if (ks < 7) STAGE(cur ^ 1, (ks+1)*32);
        // ---- B-fragment from LDS
        const int hwl = wv*16 + la;
        union { u32 u[4]; bf16x8 v; } Bf;
        #pragma unroll
        for (int j = 0; j < 4; ++j) {
            const int cb = ((j >> 1) << 4) + hi*4 + ((j & 1) << 1);
            Bf.u[j] = (u32)f2bf(lds[cur][cb][hwl]) |
                      ((u32)f2bf(lds[cur][cb+1][hwl]) << 16);
        }
        // ---- A-fragments interleaved with MFMA (low VGPR)
        #pragma unroll
        for (int u = 0; u < 5; ++u) {
            union { u32x4 q; bf16x8 v; } A;
            A.q = *(const u32x4*)&wbp[((ks*5 + u)*64 + l)*4];
            acc[u] = __builtin_amdgcn_mfma_f32_16x16x32_bf16(A.v, Bf.v, acc[u], 0, 0, 0);
        }
    }
#undef STAGE

    // ---- dense epilogue: repack via LDS, one contiguous 10,240-B stream
    __syncthreads();                       // all LDS reads of K-loop done
    u16* yt = (u16*)lds;                   // [64 hw][80 o] bf16 = 10,240 B
    {
        const int hwl = wv*16 + la;
        #pragma unroll
        for (int u = 0; u < 5; ++u) {
            f32x4 a = acc[u];
            u32 p0 = (u32)f2bf(a.x) | ((u32)f2bf(a.y) << 16);
            u32 p1 = (u32)f2bf(a.z) | ((u32)f2bf(a.w) << 16);
            u32x2 pk; pk.x = p0; pk.y = p1;
            *(u32x2*)&yt[hwl*80 + u*16 + hi*4] = pk;
        }
    }
    __syncthreads();
    const u32x4* src128 = (const u32x4*)yt;
    u32x4* dst128 = (u32x4*)(pf + (size_t)(bn*HW_ + hw0)*80);
    #pragma unroll
    for (int i = 0; i < 3; ++i) {
        int k = t + i*256;
        if (k < 640) dst128[k] = src128[k];   // 640 x 16 B = 10,240 B
    }
}

// --------------- K3: inline projection + gather + bias -> ybf(bf16), + stats
// 640 threads (10 waves): doubles gather MLP, halves the serial i-loop.
// XCD-swizzled (bijective, nwg=1250=8*156+2) for pf L2 locality.
__global__ __launch_bounds__(640) void k3_gather(const float* __restrict__ ws,
                                                 const float* __restrict__ lidar_aug,
                                                 const float* __restrict__ points,
                                                 const u16* __restrict__ pf,
                                                 const float* __restrict__ conv_b,
                                                 u16* __restrict__ ybf,
                                                 float* __restrict__ part)
{
    __shared__ int   idx_s[256];
    __shared__ float w_s[256];
    __shared__ float y_s[OUTC_][65];
    const int wlin = blockIdx.y*625 + blockIdx.x;
    const int q = NBLK3_ >> 3, r = NBLK3_ & 7;      // 156, 2
    const int xcd = wlin & 7, iw = wlin >> 3;
    const int wg = (xcd < r) ? xcd*(q+1) + iw : r*(q+1) + (xcd - r)*q + iw;
    const int b = wg / 625;
    const int tile = wg - b*625;
    int t = threadIdx.x;
    if (t < 256) {
        // ---- points load (issue first)
        int izl = t >> 6, p = t & 63;
        w_s[izl*64 + p] = points[b*V_ + izl*NPOS_ + tile*64 + p];
        // ---- inline voxel -> camera-index projection
        int v = tile*256 + t;
        int ixy = v >> 2;
        int iz  = v & 3;
        int ix = ixy / NY_;
        int iy = ixy - ix*NY_;
        float x = ix*0.5f - 50.f;
        float y = iy*0.5f - 50.f;
        float z = iz*1.5f - 4.f;
        const float* la = lidar_aug + b*16;
        float gx = x - la[3], gy = y - la[7], gz = z - la[11];
        float px = fmaf(la[8],  gz, fmaf(la[4], gy, fmaf(la[0], gx, 0.f)));
        float py = fmaf(la[9],  gz, fmaf(la[5], gy, fmaf(la[1], gx, 0.f)));
        float pz = fmaf(la[10], gz, fmaf(la[6], gy, fmaf(la[2], gx, 0.f)));
        int best = -1;
        #pragma unroll
        for (int n = 0; n < NCAM_; ++n) {
            const float* P = ws + WS_PROJ + (b*NCAM_ + n)*12;
            float t0 = fmaf(P[3], 1.f, fmaf(P[2],  pz, fmaf(P[1], py, fmaf(P[0], px, 0.f))));
            float t1 = fmaf(P[7], 1.f, fmaf(P[6],  pz, fmaf(P[5], py, fmaf(P[4], px, 0.f))));
            float t2 = fmaf(P[11],1.f, fmaf(P[10], pz, fmaf(P[9], py, fmaf(P[8], px, 0.f))));
            float u = t0/t2 + ws[WS_IMGT + (b*NCAM_+n)*2 + 0];
            float w = t1/t2 + ws[WS_IMGT + (b*NCAM_+n)*2 + 1];
            int uf = (int)rintf(u*0.25f);
            int vf = (int)rintf(w*0.25f);
            if (uf >= 0 && vf >= 0 && uf < WF_ && vf < HF_ && t2 > 0.f)
                best = n*HW_ + vf*WF_ + uf;
        }
        idx_s[t] = best;
    }
    __syncthreads();
    int o  = t % 80;
    int pg = t / 80;             // 0..7
    float bias = conv_b[o];
    const u16* pfb = pf + (size_t)b*(NCAM_*HW_)*80;
    for (int i = 0; i < 8; ++i) {
        int p = pg*8 + i;
        float acc = bias;
        #pragma unroll
        for (int iz = 0; iz < 4; ++iz) {
            int g = idx_s[p*4 + iz];
            if (g >= 0) acc = fmaf(w_s[iz*64 + p], bf2f(pfb[(size_t)g*80 + o]), acc);
        }
        y_s[o][p] = acc;
    }
    __syncthreads();
    // ---- coalesced bf16 y write (pairs packed to u32)
    u16* yb = ybf + (size_t)b*OUTC_*NPOS_ + tile*64;
    for (int lq = t; lq < OUTC_*32; lq += 640) {
        int oo = lq >> 5, p2 = (lq & 31) << 1;
        u32 pk = (u32)f2bf(y_s[oo][p2]) | ((u32)f2bf(y_s[oo][p2+1]) << 16);
        *(u32*)&yb[(size_t)oo*NPOS_ + p2] = pk;
    }
    // ---- per-block BN partial sums (80 ch x 1250 blocks), from f32 y_s
    int oo = t >> 3, qq = t & 7;          // 640 = 80 x 8
    float s1 = 0.f, s2 = 0.f;
    #pragma unroll
    for (int i = 0; i < 8; ++i) {
        float v = y_s[oo][qq*8 + i];
        s1 += v; s2 += v*v;
    }
    s1 += __shfl_xor(s1, 1, 8); s2 += __shfl_xor(s2, 1, 8);
    s1 += __shfl_xor(s1, 2, 8); s2 += __shfl_xor(s2, 2, 8);
    s1 += __shfl_xor(s1, 4, 8); s2 += __shfl_xor(s2, 4, 8);
    if (qq == 0) {
        int bb = b*625 + tile;
        part[oo*NBLK3_ + bb] = s1;
        part[OUTC_*NBLK3_ + oo*NBLK3_ + bb] = s2;
    }
}

// ---------------------------------- K4: reduce partials -> scale/shift
__global__ __launch_bounds__(256) void k4_final(const float* __restrict__ part,
                                                const float* __restrict__ gamma,
                                                const float* __restrict__ beta,
                                                float* __restrict__ ws)
{
    int o = blockIdx.x;
    int t = threadIdx.x;
    float s1 = 0.f, s2 = 0.f;
    for (int j = t; j < NBLK3_; j += 256) {
        s1 += part[o*NBLK3_ + j];
        s2 += part[OUTC_*NBLK3_ + o*NBLK3_ + j];
    }
    __shared__ float r1[256], r2[256];
    r1[t] = s1; r2[t] = s2;
    __syncthreads();
    for (int s = 128; s > 0; s >>= 1) {
        if (t < s) { r1[t] += r1[t+s]; r2[t] += r2[t+s]; }
        __syncthreads();
    }
    if (t == 0) {
        const float invN = 1.f/(float)(B_*NPOS_);
        float mean = r1[0]*invN;
        float var  = r2[0]*invN - mean*mean;
        float inv  = rsqrtf(var + 1e-5f);
        float sc   = gamma[o]*inv;
        ws[WS_SCALE + o] = sc;
        ws[WS_SHIFT + o] = beta[o] - mean*sc;
    }
}

// ------------------------------- K5: affine + ReLU, bf16 y -> f32 out
__global__ __launch_bounds__(256) void k5_norm(const u32* __restrict__ ybf,
                                               const float* __restrict__ ws,
                                               float* __restrict__ out)
{
    int gid = blockIdx.x*256 + threadIdx.x;
    int f = gid*8;
    if (f >= B_*OUTC_*NPOS_) return;
    int o = (f / NPOS_) % OUTC_;     // 40000 % 8 == 0 -> whole group shares o
    float sc = ws[WS_SCALE + o], sh = ws[WS_SHIFT + o];
    u32x4 v = *(const u32x4*)&ybf[gid*4];
    float4 r0, r1;
    r0.x = fmaxf(fmaf(bf2f((u16)(v.x & 0xffff)), sc, sh), 0.f);
    r0.y = fmaxf(fmaf(bf2f((u16)(v.x >> 16)),    sc, sh), 0.f);
    r0.z = fmaxf(fmaf(bf2f((u16)(v.y & 0xffff)), sc, sh), 0.f);
    r0.w = fmaxf(fmaf(bf2f((u16)(v.y >> 16)),    sc, sh), 0.f);
    r1.x = fmaxf(fmaf(bf2f((u16)(v.z & 0xffff)), sc, sh), 0.f);
    r1.y = fmaxf(fmaf(bf2f((u16)(v.z >> 16)),    sc, sh), 0.f);
    r1.z = fmaxf(fmaf(bf2f((u16)(v.w & 0xffff)), sc, sh), 0.f);
    r1.w = fmaxf(fmaf(bf2f((u16)(v.w >> 16)),    sc, sh), 0.f);
    *(float4*)&out[f]     = r0;
    *(float4*)&out[f + 4] = r1;
}

extern "C" void kernel_launch(void* const* d_in, const int* in_sizes, int n_in,
                              void* d_out, int out_size, void* d_ws, size_t ws_size,
                              hipStream_t stream) {
    (void)in_sizes; (void)n_in; (void)out_size; (void)ws_size;
    const float* feat      = (const float*)d_in[0];
    const float* points    = (const float*)d_in[1];
    const float* l2i       = (const float*)d_in[2];
    const float* img_aug   = (const float*)d_in[3];
    const float* lidar_aug = (const float*)d_in[4];
    const float* conv_w    = (const float*)d_in[5];
    const float* conv_b    = (const float*)d_in[6];
    const float* gamma     = (const float*)d_in[7];
    const float* beta      = (const float*)d_in[8];
    float* out = (float*)d_out;
    float* wsf = (float*)d_ws;
    u32*   wbp = (u32*)(wsf + WS_WB);
    u16*   pf  = (u16*)(wsf + WS_PF);
    float* part = wsf + WS_PART;
    u16*   ybf = (u16*)(wsf + WS_YBF);

    hipLaunchKernelGGL(k0_prep, dim3(1), dim3(256), 0, stream, l2i, img_aug, conv_w, wsf);
    hipLaunchKernelGGL(k2_mfma, dim3(HW_/64, B_*NCAM_), dim3(256), 0, stream, feat, wbp, pf);
    hipLaunchKernelGGL(k3_gather, dim3(625, B_), dim3(640), 0, stream, wsf, lidar_aug, points, pf, conv_b, ybf, part);
    hipLaunchKernelGGL(k4_final, dim3(OUTC_), dim3(256), 0, stream, part, gamma, beta, wsf);
    hipLaunchKernelGGL(k5_norm, dim3((B_*OUTC_*NPOS_/8)/256 + 1, 1), dim3(256), 0, stream, (const u32*)ybf, wsf, out);
}

// Round 16
// 73.250 us; speedup vs baseline: 1.3484x; 1.2137x over previous
//
#include <hip/hip_runtime.h>

#define B_ 2
#define NCAM_ 6
#define C_ 256
#define HF_ 64
#define WF_ 176
#define NX_ 200
#define NY_ 200
#define NZ_ 4
#define V_ (NX_*NY_*NZ_)      /* 160000 */
#define HW_ (HF_*WF_)         /* 11264 */
#define OUTC_ 80
#define NPOS_ (NX_*NY_)       /* 40000 */
#define NBLK3_ 1250           /* k3 blocks = 625*2 */

typedef unsigned short u16;
typedef unsigned int   u32;
typedef __attribute__((ext_vector_type(8))) short bf16x8;
typedef __attribute__((ext_vector_type(4))) float f32x4;
typedef __attribute__((ext_vector_type(2))) unsigned int u32x2;
typedef __attribute__((ext_vector_type(4))) unsigned int u32x4;

/* workspace layout (float offsets) */
#define WS_PROJ 0            /* 144: [b][n][3][4] */
#define WS_IMGT 144          /* 24:  [b][n][2] */
#define WS_SCALE 256         /* 80 */
#define WS_SHIFT 336         /* 80 */
#define WS_WB   2048         /* u32[8][5][64][4] = 10240 u32 */
#define WS_PF   336384       /* u16[12*11264*80] = 5406720 floats */
#define WS_PART 5743104      /* 2*80*1250 = 200000 floats */
#define WS_YBF  5943104      /* u16[2*80*40000] = 3200000 floats */

__device__ __forceinline__ u16 f2bf(float x) {
    u32 u = __float_as_uint(x);
    u32 r = (u + 0x7fffu + ((u >> 16) & 1u)) >> 16;   // RNE
    return (u16)r;
}
__device__ __forceinline__ float bf2f(u16 v) {
    return __uint_as_float(((u32)v) << 16);
}

// ---------------------------------------------------------------- K0: prep
__global__ void k0_prep(const float* __restrict__ l2i,
                        const float* __restrict__ img_aug,
                        const float* __restrict__ conv_w,
                        float* __restrict__ ws)
{
    int t = threadIdx.x;
    if (t < B_*NCAM_*12) {
        int bn = t / 12;
        int e  = t % 12;
        int i = e >> 2, j = e & 3;
        const float* A = img_aug + bn*16;
        const float* L = l2i + bn*16;
        float acc = 0.f;
        #pragma unroll
        for (int k = 0; k < 4; ++k) {
            float a = (k < 3) ? A[i*4 + k] : 0.f;   // img_r: column 3 zeroed
            acc = fmaf(a, L[k*4 + j], acc);
        }
        ws[WS_PROJ + t] = acc;
    }
    if (t >= 192 && t < 192 + B_*NCAM_*2) {
        int s = t - 192;
        int bn = s >> 1, i = s & 1;
        ws[WS_IMGT + s] = img_aug[bn*16 + i*4 + 3];
    }
    u32* wbp = (u32*)(ws + WS_WB);
    for (int i = t; i < 8*5*64*4; i += 256) {
        int ks = i / 1280;
        int r  = i - ks*1280;
        int u  = r >> 8;
        int r2 = r & 255;
        int l  = r2 >> 2;
        int j  = r2 & 3;
        int la = l & 15, hi = l >> 4;
        int o  = u*16 + la;
        int cb = ks*32 + ((j >> 1) << 4) + hi*4 + ((j & 1) << 1);
        wbp[i] = (u32)f2bf(conv_w[o*C_ + cb]) | ((u32)f2bf(conv_w[o*C_ + cb + 1]) << 16);
    }
}

// ---------------------------- K2: pf[bn][hw][o] = W @ feat  (bf16 MFMA)
// 64-hw tile, 16 KiB dbuf, 8 blocks/CU, XCD-aware hw-block swizzle,
// dense LDS-repacked epilogue. (R12 structure — best measured, 80.9 us total)
__global__ __launch_bounds__(256, 8) void k2_mfma(const float* __restrict__ feat,
                                                  const u32* __restrict__ wbp,
                                                  u16* __restrict__ pf)
{
    __shared__ float lds[2][32][64];   // 16 KiB
    const int bn  = blockIdx.y;
    const int x   = blockIdx.x;
    const int xsw = (x & 7)*22 + (x >> 3);   // bijective over 176
    const int hw0 = xsw*64;
    const int t   = threadIdx.x;
    const int wv  = t >> 6;        // wave 0..3
    const int l   = t & 63;
    const int la  = l & 15;
    const int hi  = l >> 4;

    const float* fb = feat + (size_t)bn*C_*HW_ + hw0;

#define STAGE(buf, c0) do { \
    _Pragma("unroll") for (int i_ = 0; i_ < 2; ++i_) { \
        int r0_ = i_*16 + wv*4; \
        const float* src_ = fb + (size_t)((c0) + r0_ + (l >> 4))*HW_ + (l & 15)*4; \
        __builtin_amdgcn_global_load_lds( \
            (const __attribute__((address_space(1))) unsigned int*)src_, \
            (__attribute__((address_space(3))) unsigned int*)&lds[buf][r0_][0], \
            16, 0, 0); \
    } \
} while (0)

    f32x4 acc[5] = {};
    STAGE(0, 0);
    for (int ks = 0; ks < 8; ++ks) {
        const int cur = ks & 1;
        __syncthreads();                    // staged data for 'cur' visible
        if (ks < 7) STAGE(cur ^ 1, (ks+1)*32);
        // ---- B-fragment from LDS
        const int hwl = wv*16 + la;
        union { u32 u[4]; bf16x8 v; } Bf;
        #pragma unroll
        for (int j = 0; j < 4; ++j) {
            const int cb = ((j >> 1) << 4) + hi*4 + ((j & 1) << 1);
            Bf.u[j] = (u32)f2bf(lds[cur][cb][hwl]) |
                      ((u32)f2bf(lds[cur][cb+1][hwl]) << 16);
        }
        // ---- A-fragments interleaved with MFMA (low VGPR)
        #pragma unroll
        for (int u = 0; u < 5; ++u) {
            union { u32x4 q; bf16x8 v; } A;
            A.q = *(const u32x4*)&wbp[((ks*5 + u)*64 + l)*4];
            acc[u] = __builtin_amdgcn_mfma_f32_16x16x32_bf16(A.v, Bf.v, acc[u], 0, 0, 0);
        }
    }
#undef STAGE

    // ---- dense epilogue: repack via LDS, one contiguous 10,240-B stream
    __syncthreads();                       // all LDS reads of K-loop done
    u16* yt = (u16*)lds;                   // [64 hw][80 o] bf16 = 10,240 B
    {
        const int hwl = wv*16 + la;
        #pragma unroll
        for (int u = 0; u < 5; ++u) {
            f32x4 a = acc[u];
            u32 p0 = (u32)f2bf(a.x) | ((u32)f2bf(a.y) << 16);
            u32 p1 = (u32)f2bf(a.z) | ((u32)f2bf(a.w) << 16);
            u32x2 pk; pk.x = p0; pk.y = p1;
            *(u32x2*)&yt[hwl*80 + u*16 + hi*4] = pk;
        }
    }
    __syncthreads();
    const u32x4* src128 = (const u32x4*)yt;
    u32x4* dst128 = (u32x4*)(pf + (size_t)(bn*HW_ + hw0)*80);
    #pragma unroll
    for (int i = 0; i < 3; ++i) {
        int k = t + i*256;
        if (k < 640) dst128[k] = src128[k];   // 640 x 16 B = 10,240 B
    }
}

// --------------- K3: inline projection + gather + bias -> ybf(bf16), + stats
// R12 structure (320 threads — measured best) with ONE change: pair-channel
// u32 gathers (each thread owns channels 2o,2o+1; one aligned u32 load per
// (position, iz) instead of two u16 gathers -> half the scattered loads).
__global__ __launch_bounds__(320) void k3_gather(const float* __restrict__ ws,
                                                 const float* __restrict__ lidar_aug,
                                                 const float* __restrict__ points,
                                                 const u16* __restrict__ pf,
                                                 const float* __restrict__ conv_b,
                                                 u16* __restrict__ ybf,
                                                 float* __restrict__ part)
{
    __shared__ int   idx_s[256];
    __shared__ float w_s[256];
    __shared__ float y_s[OUTC_][65];
    const int wlin = blockIdx.y*625 + blockIdx.x;
    const int q = NBLK3_ >> 3, r = NBLK3_ & 7;      // 156, 2
    const int xcd = wlin & 7, iw = wlin >> 3;
    const int wg = (xcd < r) ? xcd*(q+1) + iw : r*(q+1) + (xcd - r)*q + iw;
    const int b = wg / 625;
    const int tile = wg - b*625;
    int t = threadIdx.x;
    if (t < 256) {
        // ---- points load (issue first)
        int izl = t >> 6, p = t & 63;
        w_s[izl*64 + p] = points[b*V_ + izl*NPOS_ + tile*64 + p];
        // ---- inline voxel -> camera-index projection
        int v = tile*256 + t;
        int ixy = v >> 2;
        int iz  = v & 3;
        int ix = ixy / NY_;
        int iy = ixy - ix*NY_;
        float x = ix*0.5f - 50.f;
        float y = iy*0.5f - 50.f;
        float z = iz*1.5f - 4.f;
        const float* la = lidar_aug + b*16;
        float gx = x - la[3], gy = y - la[7], gz = z - la[11];
        float px = fmaf(la[8],  gz, fmaf(la[4], gy, fmaf(la[0], gx, 0.f)));
        float py = fmaf(la[9],  gz, fmaf(la[5], gy, fmaf(la[1], gx, 0.f)));
        float pz = fmaf(la[10], gz, fmaf(la[6], gy, fmaf(la[2], gx, 0.f)));
        int best = -1;
        #pragma unroll
        for (int n = 0; n < NCAM_; ++n) {
            const float* P = ws + WS_PROJ + (b*NCAM_ + n)*12;
            float t0 = fmaf(P[3], 1.f, fmaf(P[2],  pz, fmaf(P[1], py, fmaf(P[0], px, 0.f))));
            float t1 = fmaf(P[7], 1.f, fmaf(P[6],  pz, fmaf(P[5], py, fmaf(P[4], px, 0.f))));
            float t2 = fmaf(P[11],1.f, fmaf(P[10], pz, fmaf(P[9], py, fmaf(P[8], px, 0.f))));
            float u = t0/t2 + ws[WS_IMGT + (b*NCAM_+n)*2 + 0];
            float w = t1/t2 + ws[WS_IMGT + (b*NCAM_+n)*2 + 1];
            int uf = (int)rintf(u*0.25f);
            int vf = (int)rintf(w*0.25f);
            if (uf >= 0 && vf >= 0 && uf < WF_ && vf < HF_ && t2 > 0.f)
                best = n*HW_ + vf*WF_ + uf;
        }
        idx_s[t] = best;
    }
    __syncthreads();
    // ---- gather: thread owns channels (og, og+1) for 8 positions
    int og = (t % 40)*2;
    int pg = t / 40;             // 0..7
    float bias0 = conv_b[og], bias1 = conv_b[og+1];
    const u16* pfb = pf + (size_t)b*(NCAM_*HW_)*80;
    for (int i = 0; i < 8; ++i) {
        int p = pg*8 + i;
        float a0 = bias0, a1 = bias1;
        #pragma unroll
        for (int iz = 0; iz < 4; ++iz) {
            int g = idx_s[p*4 + iz];
            if (g >= 0) {
                u32 w2 = *(const u32*)&pfb[(size_t)g*80 + og];
                float wgt = w_s[iz*64 + p];
                a0 = fmaf(wgt, bf2f((u16)(w2 & 0xffff)), a0);
                a1 = fmaf(wgt, bf2f((u16)(w2 >> 16)),    a1);
            }
        }
        y_s[og][p]   = a0;
        y_s[og+1][p] = a1;
    }
    __syncthreads();
    // ---- coalesced bf16 y write (pairs packed to u32)
    u16* yb = ybf + (size_t)b*OUTC_*NPOS_ + tile*64;
    for (int lq = t; lq < OUTC_*32; lq += 320) {
        int oo = lq >> 5, p2 = (lq & 31) << 1;
        u32 pk = (u32)f2bf(y_s[oo][p2]) | ((u32)f2bf(y_s[oo][p2+1]) << 16);
        *(u32*)&yb[(size_t)oo*NPOS_ + p2] = pk;
    }
    // ---- per-block BN partial sums (80 ch x 1250 blocks), from f32 y_s
    int oo = t >> 2, qq = t & 3;
    float s1 = 0.f, s2 = 0.f;
    #pragma unroll
    for (int i = 0; i < 16; ++i) {
        float v = y_s[oo][qq*16 + i];
        s1 += v; s2 += v*v;
    }
    s1 += __shfl_xor(s1, 1, 4); s2 += __shfl_xor(s2, 1, 4);
    s1 += __shfl_xor(s1, 2, 4); s2 += __shfl_xor(s2, 2, 4);
    if (qq == 0) {
        int bb = b*625 + tile;
        part[oo*NBLK3_ + bb] = s1;
        part[OUTC_*NBLK3_ + oo*NBLK3_ + bb] = s2;
    }
}

// ---------------------------------- K4: reduce partials -> scale/shift
__global__ __launch_bounds__(256) void k4_final(const float* __restrict__ part,
                                                const float* __restrict__ gamma,
                                                const float* __restrict__ beta,
                                                float* __restrict__ ws)
{
    int o = blockIdx.x;
    int t = threadIdx.x;
    float s1 = 0.f, s2 = 0.f;
    for (int j = t; j < NBLK3_; j += 256) {
        s1 += part[o*NBLK3_ + j];
        s2 += part[OUTC_*NBLK3_ + o*NBLK3_ + j];
    }
    __shared__ float r1[256], r2[256];
    r1[t] = s1; r2[t] = s2;
    __syncthreads();
    for (int s = 128; s > 0; s >>= 1) {
        if (t < s) { r1[t] += r1[t+s]; r2[t] += r2[t+s]; }
        __syncthreads();
    }
    if (t == 0) {
        const float invN = 1.f/(float)(B_*NPOS_);
        float mean = r1[0]*invN;
        float var  = r2[0]*invN - mean*mean;
        float inv  = rsqrtf(var + 1e-5f);
        float sc   = gamma[o]*inv;
        ws[WS_SCALE + o] = sc;
        ws[WS_SHIFT + o] = beta[o] - mean*sc;
    }
}

// ------------------------------- K5: affine + ReLU, bf16 y -> f32 out
__global__ __launch_bounds__(256) void k5_norm(const u32* __restrict__ ybf,
                                               const float* __restrict__ ws,
                                               float* __restrict__ out)
{
    int gid = blockIdx.x*256 + threadIdx.x;
    int f = gid*8;
    if (f >= B_*OUTC_*NPOS_) return;
    int o = (f / NPOS_) % OUTC_;     // 40000 % 8 == 0 -> whole group shares o
    float sc = ws[WS_SCALE + o], sh = ws[WS_SHIFT + o];
    u32x4 v = *(const u32x4*)&ybf[gid*4];
    float4 r0, r1;
    r0.x = fmaxf(fmaf(bf2f((u16)(v.x & 0xffff)), sc, sh), 0.f);
    r0.y = fmaxf(fmaf(bf2f((u16)(v.x >> 16)),    sc, sh), 0.f);
    r0.z = fmaxf(fmaf(bf2f((u16)(v.y & 0xffff)), sc, sh), 0.f);
    r0.w = fmaxf(fmaf(bf2f((u16)(v.y >> 16)),    sc, sh), 0.f);
    r1.x = fmaxf(fmaf(bf2f((u16)(v.z & 0xffff)), sc, sh), 0.f);
    r1.y = fmaxf(fmaf(bf2f((u16)(v.z >> 16)),    sc, sh), 0.f);
    r1.z = fmaxf(fmaf(bf2f((u16)(v.w & 0xffff)), sc, sh), 0.f);
    r1.w = fmaxf(fmaf(bf2f((u16)(v.w >> 16)),    sc, sh), 0.f);
    *(float4*)&out[f]     = r0;
    *(float4*)&out[f + 4] = r1;
}

extern "C" void kernel_launch(void* const* d_in, const int* in_sizes, int n_in,
                              void* d_out, int out_size, void* d_ws, size_t ws_size,
                              hipStream_t stream) {
    (void)in_sizes; (void)n_in; (void)out_size; (void)ws_size;
    const float* feat      = (const float*)d_in[0];
    const float* points    = (const float*)d_in[1];
    const float* l2i       = (const float*)d_in[2];
    const float* img_aug   = (const float*)d_in[3];
    const float* lidar_aug = (const float*)d_in[4];
    const float* conv_w    = (const float*)d_in[5];
    const float* conv_b    = (const float*)d_in[6];
    const float* gamma     = (const float*)d_in[7];
    const float* beta      = (const float*)d_in[8];
    float* out = (float*)d_out;
    float* wsf = (float*)d_ws;
    u32*   wbp = (u32*)(wsf + WS_WB);
    u16*   pf  = (u16*)(wsf + WS_PF);
    float* part = wsf + WS_PART;
    u16*   ybf = (u16*)(wsf + WS_YBF);

    hipLaunchKernelGGL(k0_prep, dim3(1), dim3(256), 0, stream, l2i, img_aug, conv_w, wsf);
    hipLaunchKernelGGL(k2_mfma, dim3(HW_/64, B_*NCAM_), dim3(256), 0, stream, feat, wbp, pf);
    hipLaunchKernelGGL(k3_gather, dim3(625, B_), dim3(320), 0, stream, wsf, lidar_aug, points, pf, conv_b, ybf, part);
    hipLaunchKernelGGL(k4_final, dim3(OUTC_), dim3(256), 0, stream, part, gamma, beta, wsf);
    hipLaunchKernelGGL(k5_norm, dim3((B_*OUTC_*NPOS_/8)/256 + 1, 1), dim3(256), 0, stream, (const u32*)ybf, wsf, out);
}

// Round 17
// 69.054 us; speedup vs baseline: 1.4303x; 1.0608x over previous
//
#include <hip/hip_runtime.h>

#define B_ 2
#define NCAM_ 6
#define C_ 256
#define HF_ 64
#define WF_ 176
#define NX_ 200
#define NY_ 200
#define NZ_ 4
#define V_ (NX_*NY_*NZ_)      /* 160000 */
#define HW_ (HF_*WF_)         /* 11264 */
#define OUTC_ 80
#define NPOS_ (NX_*NY_)       /* 40000 */
#define NBLK3_ 1250           /* k3 blocks = 625*2 */

typedef unsigned short u16;
typedef unsigned int   u32;
typedef __attribute__((ext_vector_type(8))) short bf16x8;
typedef __attribute__((ext_vector_type(4))) float f32x4;
typedef __attribute__((ext_vector_type(2))) unsigned int u32x2;
typedef __attribute__((ext_vector_type(4))) unsigned int u32x4;

/* workspace layout (float offsets) */
#define WS_PROJ 0            /* 144: [b][n][3][4] */
#define WS_IMGT 144          /* 24:  [b][n][2] */
#define WS_SCALE 256         /* 80 */
#define WS_SHIFT 336         /* 80 */
#define WS_WB   2048         /* u32[8][5][64][4] = 10240 u32 */
#define WS_PF   336384       /* u16[12*11264*80] = 5406720 floats */
#define WS_PART 5743104      /* 2*80*1250 = 200000 floats */
#define WS_YBF  5943104      /* u16[2*80*40000] = 3200000 floats */

__device__ __forceinline__ u16 f2bf(float x) {
    u32 u = __float_as_uint(x);
    u32 r = (u + 0x7fffu + ((u >> 16) & 1u)) >> 16;   // RNE
    return (u16)r;
}
__device__ __forceinline__ float bf2f(u16 v) {
    return __uint_as_float(((u32)v) << 16);
}

// ---------------------------------------------------------------- K0: prep
__global__ void k0_prep(const float* __restrict__ l2i,
                        const float* __restrict__ img_aug,
                        const float* __restrict__ conv_w,
                        float* __restrict__ ws)
{
    int t = threadIdx.x;
    if (t < B_*NCAM_*12) {
        int bn = t / 12;
        int e  = t % 12;
        int i = e >> 2, j = e & 3;
        const float* A = img_aug + bn*16;
        const float* L = l2i + bn*16;
        float acc = 0.f;
        #pragma unroll
        for (int k = 0; k < 4; ++k) {
            float a = (k < 3) ? A[i*4 + k] : 0.f;   // img_r: column 3 zeroed
            acc = fmaf(a, L[k*4 + j], acc);
        }
        ws[WS_PROJ + t] = acc;
    }
    if (t >= 192 && t < 192 + B_*NCAM_*2) {
        int s = t - 192;
        int bn = s >> 1, i = s & 1;
        ws[WS_IMGT + s] = img_aug[bn*16 + i*4 + 3];
    }
    u32* wbp = (u32*)(ws + WS_WB);
    for (int i = t; i < 8*5*64*4; i += 256) {
        int ks = i / 1280;
        int r  = i - ks*1280;
        int u  = r >> 8;
        int r2 = r & 255;
        int l  = r2 >> 2;
        int j  = r2 & 3;
        int la = l & 15, hi = l >> 4;
        int o  = u*16 + la;
        int cb = ks*32 + ((j >> 1) << 4) + hi*4 + ((j & 1) << 1);
        wbp[i] = (u32)f2bf(conv_w[o*C_ + cb]) | ((u32)f2bf(conv_w[o*C_ + cb + 1]) << 16);
    }
}

// ---------------------------- K2: pf[bn][hw][o] = W @ feat  (bf16 MFMA)
// 64-hw tile, 16 KiB dbuf, 8 blocks/CU, XCD-aware hw-block swizzle,
// dense LDS-repacked epilogue. (best measured structure)
__global__ __launch_bounds__(256, 8) void k2_mfma(const float* __restrict__ feat,
                                                  const u32* __restrict__ wbp,
                                                  u16* __restrict__ pf)
{
    __shared__ float lds[2][32][64];   // 16 KiB
    const int bn  = blockIdx.y;
    const int x   = blockIdx.x;
    const int xsw = (x & 7)*22 + (x >> 3);   // bijective over 176
    const int hw0 = xsw*64;
    const int t   = threadIdx.x;
    const int wv  = t >> 6;        // wave 0..3
    const int l   = t & 63;
    const int la  = l & 15;
    const int hi  = l >> 4;

    const float* fb = feat + (size_t)bn*C_*HW_ + hw0;

#define STAGE(buf, c0) do { \
    _Pragma("unroll") for (int i_ = 0; i_ < 2; ++i_) { \
        int r0_ = i_*16 + wv*4; \
        const float* src_ = fb + (size_t)((c0) + r0_ + (l >> 4))*HW_ + (l & 15)*4; \
        __builtin_amdgcn_global_load_lds( \
            (const __attribute__((address_space(1))) unsigned int*)src_, \
            (__attribute__((address_space(3))) unsigned int*)&lds[buf][r0_][0], \
            16, 0, 0); \
    } \
} while (0)

    f32x4 acc[5] = {};
    STAGE(0, 0);
    for (int ks = 0; ks < 8; ++ks) {
        const int cur = ks & 1;
        __syncthreads();                    // staged data for 'cur' visible
        if (ks < 7) STAGE(cur ^ 1, (ks+1)*32);
        // ---- B-fragment from LDS
        const int hwl = wv*16 + la;
        union { u32 u[4]; bf16x8 v; } Bf;
        #pragma unroll
        for (int j = 0; j < 4; ++j) {
            const int cb = ((j >> 1) << 4) + hi*4 + ((j & 1) << 1);
            Bf.u[j] = (u32)f2bf(lds[cur][cb][hwl]) |
                      ((u32)f2bf(lds[cur][cb+1][hwl]) << 16);
        }
        // ---- A-fragments interleaved with MFMA (low VGPR)
        #pragma unroll
        for (int u = 0; u < 5; ++u) {
            union { u32x4 q; bf16x8 v; } A;
            A.q = *(const u32x4*)&wbp[((ks*5 + u)*64 + l)*4];
            acc[u] = __builtin_amdgcn_mfma_f32_16x16x32_bf16(A.v, Bf.v, acc[u], 0, 0, 0);
        }
    }
#undef STAGE

    // ---- dense epilogue: repack via LDS, one contiguous 10,240-B stream
    __syncthreads();                       // all LDS reads of K-loop done
    u16* yt = (u16*)lds;                   // [64 hw][80 o] bf16 = 10,240 B
    {
        const int hwl = wv*16 + la;
        #pragma unroll
        for (int u = 0; u < 5; ++u) {
            f32x4 a = acc[u];
            u32 p0 = (u32)f2bf(a.x) | ((u32)f2bf(a.y) << 16);
            u32 p1 = (u32)f2bf(a.z) | ((u32)f2bf(a.w) << 16);
            u32x2 pk; pk.x = p0; pk.y = p1;
            *(u32x2*)&yt[hwl*80 + u*16 + hi*4] = pk;
        }
    }
    __syncthreads();
    const u32x4* src128 = (const u32x4*)yt;
    u32x4* dst128 = (u32x4*)(pf + (size_t)(bn*HW_ + hw0)*80);
    #pragma unroll
    for (int i = 0; i < 3; ++i) {
        int k = t + i*256;
        if (k < 640) dst128[k] = src128[k];   // 640 x 16 B = 10,240 B
    }
}

// --------------- K3: inline projection + gather + bias -> ybf(bf16), + stats
// 320 threads; QUAD-channel u32x2 gathers: thread owns channels og..og+3,
// 4 positions -> 16 scattered 8-B loads per thread (was 32 x 4-B).
__global__ __launch_bounds__(320) void k3_gather(const float* __restrict__ ws,
                                                 const float* __restrict__ lidar_aug,
                                                 const float* __restrict__ points,
                                                 const u16* __restrict__ pf,
                                                 const float* __restrict__ conv_b,
                                                 u16* __restrict__ ybf,
                                                 float* __restrict__ part)
{
    __shared__ int   idx_s[256];
    __shared__ float w_s[256];
    __shared__ float y_s[OUTC_][65];
    const int wlin = blockIdx.y*625 + blockIdx.x;
    const int q = NBLK3_ >> 3, r = NBLK3_ & 7;      // 156, 2
    const int xcd = wlin & 7, iw = wlin >> 3;
    const int wg = (xcd < r) ? xcd*(q+1) + iw : r*(q+1) + (xcd - r)*q + iw;
    const int b = wg / 625;
    const int tile = wg - b*625;
    int t = threadIdx.x;
    if (t < 256) {
        // ---- points load (issue first)
        int izl = t >> 6, p = t & 63;
        w_s[izl*64 + p] = points[b*V_ + izl*NPOS_ + tile*64 + p];
        // ---- inline voxel -> camera-index projection
        int v = tile*256 + t;
        int ixy = v >> 2;
        int iz  = v & 3;
        int ix = ixy / NY_;
        int iy = ixy - ix*NY_;
        float x = ix*0.5f - 50.f;
        float y = iy*0.5f - 50.f;
        float z = iz*1.5f - 4.f;
        const float* la = lidar_aug + b*16;
        float gx = x - la[3], gy = y - la[7], gz = z - la[11];
        float px = fmaf(la[8],  gz, fmaf(la[4], gy, fmaf(la[0], gx, 0.f)));
        float py = fmaf(la[9],  gz, fmaf(la[5], gy, fmaf(la[1], gx, 0.f)));
        float pz = fmaf(la[10], gz, fmaf(la[6], gy, fmaf(la[2], gx, 0.f)));
        int best = -1;
        #pragma unroll
        for (int n = 0; n < NCAM_; ++n) {
            const float* P = ws + WS_PROJ + (b*NCAM_ + n)*12;
            float t0 = fmaf(P[3], 1.f, fmaf(P[2],  pz, fmaf(P[1], py, fmaf(P[0], px, 0.f))));
            float t1 = fmaf(P[7], 1.f, fmaf(P[6],  pz, fmaf(P[5], py, fmaf(P[4], px, 0.f))));
            float t2 = fmaf(P[11],1.f, fmaf(P[10], pz, fmaf(P[9], py, fmaf(P[8], px, 0.f))));
            float u = t0/t2 + ws[WS_IMGT + (b*NCAM_+n)*2 + 0];
            float w = t1/t2 + ws[WS_IMGT + (b*NCAM_+n)*2 + 1];
            int uf = (int)rintf(u*0.25f);
            int vf = (int)rintf(w*0.25f);
            if (uf >= 0 && vf >= 0 && uf < WF_ && vf < HF_ && t2 > 0.f)
                best = n*HW_ + vf*WF_ + uf;
        }
        idx_s[t] = best;
    }
    __syncthreads();
    // ---- gather: thread owns channels og..og+3 for 4 positions
    int og = (t % 20)*4;
    int pg = t / 20;             // 0..15
    float b0 = conv_b[og], b1 = conv_b[og+1], b2 = conv_b[og+2], b3 = conv_b[og+3];
    const u16* pfb = pf + (size_t)b*(NCAM_*HW_)*80;
    for (int i = 0; i < 4; ++i) {
        int p = pg*4 + i;
        float a0 = b0, a1 = b1, a2 = b2, a3 = b3;
        #pragma unroll
        for (int iz = 0; iz < 4; ++iz) {
            int g = idx_s[p*4 + iz];
            if (g >= 0) {
                u32x2 w2 = *(const u32x2*)&pfb[(size_t)g*80 + og];
                float wgt = w_s[iz*64 + p];
                a0 = fmaf(wgt, bf2f((u16)(w2.x & 0xffff)), a0);
                a1 = fmaf(wgt, bf2f((u16)(w2.x >> 16)),    a1);
                a2 = fmaf(wgt, bf2f((u16)(w2.y & 0xffff)), a2);
                a3 = fmaf(wgt, bf2f((u16)(w2.y >> 16)),    a3);
            }
        }
        y_s[og][p]   = a0;
        y_s[og+1][p] = a1;
        y_s[og+2][p] = a2;
        y_s[og+3][p] = a3;
    }
    __syncthreads();
    // ---- coalesced bf16 y write (pairs packed to u32)
    u16* yb = ybf + (size_t)b*OUTC_*NPOS_ + tile*64;
    for (int lq = t; lq < OUTC_*32; lq += 320) {
        int oo = lq >> 5, p2 = (lq & 31) << 1;
        u32 pk = (u32)f2bf(y_s[oo][p2]) | ((u32)f2bf(y_s[oo][p2+1]) << 16);
        *(u32*)&yb[(size_t)oo*NPOS_ + p2] = pk;
    }
    // ---- per-block BN partial sums (80 ch x 1250 blocks), from f32 y_s
    int oo = t >> 2, qq = t & 3;
    float s1 = 0.f, s2 = 0.f;
    #pragma unroll
    for (int i = 0; i < 16; ++i) {
        float v = y_s[oo][qq*16 + i];
        s1 += v; s2 += v*v;
    }
    s1 += __shfl_xor(s1, 1, 4); s2 += __shfl_xor(s2, 1, 4);
    s1 += __shfl_xor(s1, 2, 4); s2 += __shfl_xor(s2, 2, 4);
    if (qq == 0) {
        int bb = b*625 + tile;
        part[oo*NBLK3_ + bb] = s1;
        part[OUTC_*NBLK3_ + oo*NBLK3_ + bb] = s2;
    }
}

// ---------------------------------- K4: reduce partials -> scale/shift
__global__ __launch_bounds__(256) void k4_final(const float* __restrict__ part,
                                                const float* __restrict__ gamma,
                                                const float* __restrict__ beta,
                                                float* __restrict__ ws)
{
    int o = blockIdx.x;
    int t = threadIdx.x;
    float s1 = 0.f, s2 = 0.f;
    for (int j = t; j < NBLK3_; j += 256) {
        s1 += part[o*NBLK3_ + j];
        s2 += part[OUTC_*NBLK3_ + o*NBLK3_ + j];
    }
    __shared__ float r1[256], r2[256];
    r1[t] = s1; r2[t] = s2;
    __syncthreads();
    for (int s = 128; s > 0; s >>= 1) {
        if (t < s) { r1[t] += r1[t+s]; r2[t] += r2[t+s]; }
        __syncthreads();
    }
    if (t == 0) {
        const float invN = 1.f/(float)(B_*NPOS_);
        float mean = r1[0]*invN;
        float var  = r2[0]*invN - mean*mean;
        float inv  = rsqrtf(var + 1e-5f);
        float sc   = gamma[o]*inv;
        ws[WS_SCALE + o] = sc;
        ws[WS_SHIFT + o] = beta[o] - mean*sc;
    }
}

// ------------------------------- K5: affine + ReLU, bf16 y -> f32 out
__global__ __launch_bounds__(256) void k5_norm(const u32* __restrict__ ybf,
                                               const float* __restrict__ ws,
                                               float* __restrict__ out)
{
    int gid = blockIdx.x*256 + threadIdx.x;
    int f = gid*8;
    if (f >= B_*OUTC_*NPOS_) return;
    int o = (f / NPOS_) % OUTC_;     // 40000 % 8 == 0 -> whole group shares o
    float sc = ws[WS_SCALE + o], sh = ws[WS_SHIFT + o];
    u32x4 v = *(const u32x4*)&ybf[gid*4];
    float4 r0, r1;
    r0.x = fmaxf(fmaf(bf2f((u16)(v.x & 0xffff)), sc, sh), 0.f);
    r0.y = fmaxf(fmaf(bf2f((u16)(v.x >> 16)),    sc, sh), 0.f);
    r0.z = fmaxf(fmaf(bf2f((u16)(v.y & 0xffff)), sc, sh), 0.f);
    r0.w = fmaxf(fmaf(bf2f((u16)(v.y >> 16)),    sc, sh), 0.f);
    r1.x = fmaxf(fmaf(bf2f((u16)(v.z & 0xffff)), sc, sh), 0.f);
    r1.y = fmaxf(fmaf(bf2f((u16)(v.z >> 16)),    sc, sh), 0.f);
    r1.z = fmaxf(fmaf(bf2f((u16)(v.w & 0xffff)), sc, sh), 0.f);
    r1.w = fmaxf(fmaf(bf2f((u16)(v.w >> 16)),    sc, sh), 0.f);
    *(float4*)&out[f]     = r0;
    *(float4*)&out[f + 4] = r1;
}

extern "C" void kernel_launch(void* const* d_in, const int* in_sizes, int n_in,
                              void* d_out, int out_size, void* d_ws, size_t ws_size,
                              hipStream_t stream) {
    (void)in_sizes; (void)n_in; (void)out_size; (void)ws_size;
    const float* feat      = (const float*)d_in[0];
    const float* points    = (const float*)d_in[1];
    const float* l2i       = (const float*)d_in[2];
    const float* img_aug   = (const float*)d_in[3];
    const float* lidar_aug = (const float*)d_in[4];
    const float* conv_w    = (const float*)d_in[5];
    const float* conv_b    = (const float*)d_in[6];
    const float* gamma     = (const float*)d_in[7];
    const float* beta      = (const float*)d_in[8];
    float* out = (float*)d_out;
    float* wsf = (float*)d_ws;
    u32*   wbp = (u32*)(wsf + WS_WB);
    u16*   pf  = (u16*)(wsf + WS_PF);
    float* part = wsf + WS_PART;
    u16*   ybf = (u16*)(wsf + WS_YBF);

    hipLaunchKernelGGL(k0_prep, dim3(1), dim3(256), 0, stream, l2i, img_aug, conv_w, wsf);
    hipLaunchKernelGGL(k2_mfma, dim3(HW_/64, B_*NCAM_), dim3(256), 0, stream, feat, wbp, pf);
    hipLaunchKernelGGL(k3_gather, dim3(625, B_), dim3(320), 0, stream, wsf, lidar_aug, points, pf, conv_b, ybf, part);
    hipLaunchKernelGGL(k4_final, dim3(OUTC_), dim3(256), 0, stream, part, gamma, beta, wsf);
    hipLaunchKernelGGL(k5_norm, dim3((B_*OUTC_*NPOS_/8)/256 + 1, 1), dim3(256), 0, stream, (const u32*)ybf, wsf, out);
}

// Round 18
// 66.570 us; speedup vs baseline: 1.4837x; 1.0373x over previous
//
#include <hip/hip_runtime.h>

#define B_ 2
#define NCAM_ 6
#define C_ 256
#define HF_ 64
#define WF_ 176
#define NX_ 200
#define NY_ 200
#define NZ_ 4
#define V_ (NX_*NY_*NZ_)      /* 160000 */
#define HW_ (HF_*WF_)         /* 11264 */
#define OUTC_ 80
#define NPOS_ (NX_*NY_)       /* 40000 */
#define NBLK3_ 1250           /* k3 blocks = 625*2 */

typedef unsigned short u16;
typedef unsigned int   u32;
typedef __attribute__((ext_vector_type(8))) short bf16x8;
typedef __attribute__((ext_vector_type(4))) float f32x4;
typedef __attribute__((ext_vector_type(2))) unsigned int u32x2;
typedef __attribute__((ext_vector_type(4))) unsigned int u32x4;

/* workspace layout (float offsets) */
#define WS_PROJ 0            /* 144: [b][n][3][4] */
#define WS_IMGT 144          /* 24:  [b][n][2] */
#define WS_SCALE 256         /* 80 */
#define WS_SHIFT 336         /* 80 */
#define WS_WB   2048         /* u32[8][5][64][4] = 10240 u32 */
#define WS_PF   336384       /* u16[12*11264*80] = 5406720 floats */
#define WS_PART 5743104      /* 2*80*1250 = 200000 floats */
#define WS_YBF  5943104      /* u16[2*80*40000] = 3200000 floats */

__device__ __forceinline__ u16 f2bf(float x) {
    u32 u = __float_as_uint(x);
    u32 r = (u + 0x7fffu + ((u >> 16) & 1u)) >> 16;   // RNE
    return (u16)r;
}
__device__ __forceinline__ float bf2f(u16 v) {
    return __uint_as_float(((u32)v) << 16);
}

// ---------------------------------------------------------------- K0: prep
__global__ void k0_prep(const float* __restrict__ l2i,
                        const float* __restrict__ img_aug,
                        const float* __restrict__ conv_w,
                        float* __restrict__ ws)
{
    int t = threadIdx.x;
    if (t < B_*NCAM_*12) {
        int bn = t / 12;
        int e  = t % 12;
        int i = e >> 2, j = e & 3;
        const float* A = img_aug + bn*16;
        const float* L = l2i + bn*16;
        float acc = 0.f;
        #pragma unroll
        for (int k = 0; k < 4; ++k) {
            float a = (k < 3) ? A[i*4 + k] : 0.f;   // img_r: column 3 zeroed
            acc = fmaf(a, L[k*4 + j], acc);
        }
        ws[WS_PROJ + t] = acc;
    }
    if (t >= 192 && t < 192 + B_*NCAM_*2) {
        int s = t - 192;
        int bn = s >> 1, i = s & 1;
        ws[WS_IMGT + s] = img_aug[bn*16 + i*4 + 3];
    }
    u32* wbp = (u32*)(ws + WS_WB);
    for (int i = t; i < 8*5*64*4; i += 256) {
        int ks = i / 1280;
        int r  = i - ks*1280;
        int u  = r >> 8;
        int r2 = r & 255;
        int l  = r2 >> 2;
        int j  = r2 & 3;
        int la = l & 15, hi = l >> 4;
        int o  = u*16 + la;
        int cb = ks*32 + ((j >> 1) << 4) + hi*4 + ((j & 1) << 1);
        wbp[i] = (u32)f2bf(conv_w[o*C_ + cb]) | ((u32)f2bf(conv_w[o*C_ + cb + 1]) << 16);
    }
}

// ---------------------------- K2: pf[bn][hw][o] = W @ feat  (bf16 MFMA)
// 64-hw tile, 16 KiB dbuf, 8 blocks/CU, XCD-aware hw-block swizzle,
// dense LDS-repacked epilogue. (best measured structure)
__global__ __launch_bounds__(256, 8) void k2_mfma(const float* __restrict__ feat,
                                                  const u32* __restrict__ wbp,
                                                  u16* __restrict__ pf)
{
    __shared__ float lds[2][32][64];   // 16 KiB
    const int bn  = blockIdx.y;
    const int x   = blockIdx.x;
    const int xsw = (x & 7)*22 + (x >> 3);   // bijective over 176
    const int hw0 = xsw*64;
    const int t   = threadIdx.x;
    const int wv  = t >> 6;        // wave 0..3
    const int l   = t & 63;
    const int la  = l & 15;
    const int hi  = l >> 4;

    const float* fb = feat + (size_t)bn*C_*HW_ + hw0;

#define STAGE(buf, c0) do { \
    _Pragma("unroll") for (int i_ = 0; i_ < 2; ++i_) { \
        int r0_ = i_*16 + wv*4; \
        const float* src_ = fb + (size_t)((c0) + r0_ + (l >> 4))*HW_ + (l & 15)*4; \
        __builtin_amdgcn_global_load_lds( \
            (const __attribute__((address_space(1))) unsigned int*)src_, \
            (__attribute__((address_space(3))) unsigned int*)&lds[buf][r0_][0], \
            16, 0, 0); \
    } \
} while (0)

    f32x4 acc[5] = {};
    STAGE(0, 0);
    for (int ks = 0; ks < 8; ++ks) {
        const int cur = ks & 1;
        __syncthreads();                    // staged data for 'cur' visible
        if (ks < 7) STAGE(cur ^ 1, (ks+1)*32);
        // ---- B-fragment from LDS
        const int hwl = wv*16 + la;
        union { u32 u[4]; bf16x8 v; } Bf;
        #pragma unroll
        for (int j = 0; j < 4; ++j) {
            const int cb = ((j >> 1) << 4) + hi*4 + ((j & 1) << 1);
            Bf.u[j] = (u32)f2bf(lds[cur][cb][hwl]) |
                      ((u32)f2bf(lds[cur][cb+1][hwl]) << 16);
        }
        // ---- A-fragments interleaved with MFMA (low VGPR)
        #pragma unroll
        for (int u = 0; u < 5; ++u) {
            union { u32x4 q; bf16x8 v; } A;
            A.q = *(const u32x4*)&wbp[((ks*5 + u)*64 + l)*4];
            acc[u] = __builtin_amdgcn_mfma_f32_16x16x32_bf16(A.v, Bf.v, acc[u], 0, 0, 0);
        }
    }
#undef STAGE

    // ---- dense epilogue: repack via LDS, one contiguous 10,240-B stream
    __syncthreads();                       // all LDS reads of K-loop done
    u16* yt = (u16*)lds;                   // [64 hw][80 o] bf16 = 10,240 B
    {
        const int hwl = wv*16 + la;
        #pragma unroll
        for (int u = 0; u < 5; ++u) {
            f32x4 a = acc[u];
            u32 p0 = (u32)f2bf(a.x) | ((u32)f2bf(a.y) << 16);
            u32 p1 = (u32)f2bf(a.z) | ((u32)f2bf(a.w) << 16);
            u32x2 pk; pk.x = p0; pk.y = p1;
            *(u32x2*)&yt[hwl*80 + u*16 + hi*4] = pk;
        }
    }
    __syncthreads();
    const u32x4* src128 = (const u32x4*)yt;
    u32x4* dst128 = (u32x4*)(pf + (size_t)(bn*HW_ + hw0)*80);
    #pragma unroll
    for (int i = 0; i < 3; ++i) {
        int k = t + i*256;
        if (k < 640) dst128[k] = src128[k];   // 640 x 16 B = 10,240 B
    }
}

// --------------- K3: inline projection + gather + bias -> ybf(bf16), + stats
// 320 threads; OCT-channel u32x4 gathers: thread owns channels og..og+7,
// 2 positions -> 8 scattered 16-B loads per thread (was 16 x 8-B).
__global__ __launch_bounds__(320) void k3_gather(const float* __restrict__ ws,
                                                 const float* __restrict__ lidar_aug,
                                                 const float* __restrict__ points,
                                                 const u16* __restrict__ pf,
                                                 const float* __restrict__ conv_b,
                                                 u16* __restrict__ ybf,
                                                 float* __restrict__ part)
{
    __shared__ int   idx_s[256];
    __shared__ float w_s[256];
    __shared__ float y_s[OUTC_][65];
    const int wlin = blockIdx.y*625 + blockIdx.x;
    const int q = NBLK3_ >> 3, r = NBLK3_ & 7;      // 156, 2
    const int xcd = wlin & 7, iw = wlin >> 3;
    const int wg = (xcd < r) ? xcd*(q+1) + iw : r*(q+1) + (xcd - r)*q + iw;
    const int b = wg / 625;
    const int tile = wg - b*625;
    int t = threadIdx.x;
    if (t < 256) {
        // ---- points load (issue first)
        int izl = t >> 6, p = t & 63;
        w_s[izl*64 + p] = points[b*V_ + izl*NPOS_ + tile*64 + p];
        // ---- inline voxel -> camera-index projection
        int v = tile*256 + t;
        int ixy = v >> 2;
        int iz  = v & 3;
        int ix = ixy / NY_;
        int iy = ixy - ix*NY_;
        float x = ix*0.5f - 50.f;
        float y = iy*0.5f - 50.f;
        float z = iz*1.5f - 4.f;
        const float* la = lidar_aug + b*16;
        float gx = x - la[3], gy = y - la[7], gz = z - la[11];
        float px = fmaf(la[8],  gz, fmaf(la[4], gy, fmaf(la[0], gx, 0.f)));
        float py = fmaf(la[9],  gz, fmaf(la[5], gy, fmaf(la[1], gx, 0.f)));
        float pz = fmaf(la[10], gz, fmaf(la[6], gy, fmaf(la[2], gx, 0.f)));
        int best = -1;
        #pragma unroll
        for (int n = 0; n < NCAM_; ++n) {
            const float* P = ws + WS_PROJ + (b*NCAM_ + n)*12;
            float t0 = fmaf(P[3], 1.f, fmaf(P[2],  pz, fmaf(P[1], py, fmaf(P[0], px, 0.f))));
            float t1 = fmaf(P[7], 1.f, fmaf(P[6],  pz, fmaf(P[5], py, fmaf(P[4], px, 0.f))));
            float t2 = fmaf(P[11],1.f, fmaf(P[10], pz, fmaf(P[9], py, fmaf(P[8], px, 0.f))));
            float u = t0/t2 + ws[WS_IMGT + (b*NCAM_+n)*2 + 0];
            float w = t1/t2 + ws[WS_IMGT + (b*NCAM_+n)*2 + 1];
            int uf = (int)rintf(u*0.25f);
            int vf = (int)rintf(w*0.25f);
            if (uf >= 0 && vf >= 0 && uf < WF_ && vf < HF_ && t2 > 0.f)
                best = n*HW_ + vf*WF_ + uf;
        }
        idx_s[t] = best;
    }
    __syncthreads();
    // ---- gather: thread owns channels og..og+7 for 2 positions
    int og = (t % 10)*8;
    int pg = t / 10;             // 0..31
    float bb0 = conv_b[og],   bb1 = conv_b[og+1], bb2 = conv_b[og+2], bb3 = conv_b[og+3];
    float bb4 = conv_b[og+4], bb5 = conv_b[og+5], bb6 = conv_b[og+6], bb7 = conv_b[og+7];
    const u16* pfb = pf + (size_t)b*(NCAM_*HW_)*80;
    #pragma unroll
    for (int i = 0; i < 2; ++i) {
        int p = pg*2 + i;
        float a0 = bb0, a1 = bb1, a2 = bb2, a3 = bb3;
        float a4 = bb4, a5 = bb5, a6 = bb6, a7 = bb7;
        #pragma unroll
        for (int iz = 0; iz < 4; ++iz) {
            int g = idx_s[p*4 + iz];
            if (g >= 0) {
                u32x4 w4 = *(const u32x4*)&pfb[(size_t)g*80 + og];
                float wgt = w_s[iz*64 + p];
                a0 = fmaf(wgt, bf2f((u16)(w4.x & 0xffff)), a0);
                a1 = fmaf(wgt, bf2f((u16)(w4.x >> 16)),    a1);
                a2 = fmaf(wgt, bf2f((u16)(w4.y & 0xffff)), a2);
                a3 = fmaf(wgt, bf2f((u16)(w4.y >> 16)),    a3);
                a4 = fmaf(wgt, bf2f((u16)(w4.z & 0xffff)), a4);
                a5 = fmaf(wgt, bf2f((u16)(w4.z >> 16)),    a5);
                a6 = fmaf(wgt, bf2f((u16)(w4.w & 0xffff)), a6);
                a7 = fmaf(wgt, bf2f((u16)(w4.w >> 16)),    a7);
            }
        }
        y_s[og][p]   = a0; y_s[og+1][p] = a1;
        y_s[og+2][p] = a2; y_s[og+3][p] = a3;
        y_s[og+4][p] = a4; y_s[og+5][p] = a5;
        y_s[og+6][p] = a6; y_s[og+7][p] = a7;
    }
    __syncthreads();
    // ---- coalesced bf16 y write (pairs packed to u32)
    u16* yb = ybf + (size_t)b*OUTC_*NPOS_ + tile*64;
    for (int lq = t; lq < OUTC_*32; lq += 320) {
        int oo = lq >> 5, p2 = (lq & 31) << 1;
        u32 pk = (u32)f2bf(y_s[oo][p2]) | ((u32)f2bf(y_s[oo][p2+1]) << 16);
        *(u32*)&yb[(size_t)oo*NPOS_ + p2] = pk;
    }
    // ---- per-block BN partial sums (80 ch x 1250 blocks), from f32 y_s
    int oo = t >> 2, qq = t & 3;
    float s1 = 0.f, s2 = 0.f;
    #pragma unroll
    for (int i = 0; i < 16; ++i) {
        float v = y_s[oo][qq*16 + i];
        s1 += v; s2 += v*v;
    }
    s1 += __shfl_xor(s1, 1, 4); s2 += __shfl_xor(s2, 1, 4);
    s1 += __shfl_xor(s1, 2, 4); s2 += __shfl_xor(s2, 2, 4);
    if (qq == 0) {
        int bb = b*625 + tile;
        part[oo*NBLK3_ + bb] = s1;
        part[OUTC_*NBLK3_ + oo*NBLK3_ + bb] = s2;
    }
}

// ---------------------------------- K4: reduce partials -> scale/shift
__global__ __launch_bounds__(256) void k4_final(const float* __restrict__ part,
                                                const float* __restrict__ gamma,
                                                const float* __restrict__ beta,
                                                float* __restrict__ ws)
{
    int o = blockIdx.x;
    int t = threadIdx.x;
    float s1 = 0.f, s2 = 0.f;
    for (int j = t; j < NBLK3_; j += 256) {
        s1 += part[o*NBLK3_ + j];
        s2 += part[OUTC_*NBLK3_ + o*NBLK3_ + j];
    }
    __shared__ float r1[256], r2[256];
    r1[t] = s1; r2[t] = s2;
    __syncthreads();
    for (int s = 128; s > 0; s >>= 1) {
        if (t < s) { r1[t] += r1[t+s]; r2[t] += r2[t+s]; }
        __syncthreads();
    }
    if (t == 0) {
        const float invN = 1.f/(float)(B_*NPOS_);
        float mean = r1[0]*invN;
        float var  = r2[0]*invN - mean*mean;
        float inv  = rsqrtf(var + 1e-5f);
        float sc   = gamma[o]*inv;
        ws[WS_SCALE + o] = sc;
        ws[WS_SHIFT + o] = beta[o] - mean*sc;
    }
}

// ------------------------------- K5: affine + ReLU, bf16 y -> f32 out
__global__ __launch_bounds__(256) void k5_norm(const u32* __restrict__ ybf,
                                               const float* __restrict__ ws,
                                               float* __restrict__ out)
{
    int gid = blockIdx.x*256 + threadIdx.x;
    int f = gid*8;
    if (f >= B_*OUTC_*NPOS_) return;
    int o = (f / NPOS_) % OUTC_;     // 40000 % 8 == 0 -> whole group shares o
    float sc = ws[WS_SCALE + o], sh = ws[WS_SHIFT + o];
    u32x4 v = *(const u32x4*)&ybf[gid*4];
    float4 r0, r1;
    r0.x = fmaxf(fmaf(bf2f((u16)(v.x & 0xffff)), sc, sh), 0.f);
    r0.y = fmaxf(fmaf(bf2f((u16)(v.x >> 16)),    sc, sh), 0.f);
    r0.z = fmaxf(fmaf(bf2f((u16)(v.y & 0xffff)), sc, sh), 0.f);
    r0.w = fmaxf(fmaf(bf2f((u16)(v.y >> 16)),    sc, sh), 0.f);
    r1.x = fmaxf(fmaf(bf2f((u16)(v.z & 0xffff)), sc, sh), 0.f);
    r1.y = fmaxf(fmaf(bf2f((u16)(v.z >> 16)),    sc, sh), 0.f);
    r1.z = fmaxf(fmaf(bf2f((u16)(v.w & 0xffff)), sc, sh), 0.f);
    r1.w = fmaxf(fmaf(bf2f((u16)(v.w >> 16)),    sc, sh), 0.f);
    *(float4*)&out[f]     = r0;
    *(float4*)&out[f + 4] = r1;
}

extern "C" void kernel_launch(void* const* d_in, const int* in_sizes, int n_in,
                              void* d_out, int out_size, void* d_ws, size_t ws_size,
                              hipStream_t stream) {
    (void)in_sizes; (void)n_in; (void)out_size; (void)ws_size;
    const float* feat      = (const float*)d_in[0];
    const float* points    = (const float*)d_in[1];
    const float* l2i       = (const float*)d_in[2];
    const float* img_aug   = (const float*)d_in[3];
    const float* lidar_aug = (const float*)d_in[4];
    const float* conv_w    = (const float*)d_in[5];
    const float* conv_b    = (const float*)d_in[6];
    const float* gamma     = (const float*)d_in[7];
    const float* beta      = (const float*)d_in[8];
    float* out = (float*)d_out;
    float* wsf = (float*)d_ws;
    u32*   wbp = (u32*)(wsf + WS_WB);
    u16*   pf  = (u16*)(wsf + WS_PF);
    float* part = wsf + WS_PART;
    u16*   ybf = (u16*)(wsf + WS_YBF);

    hipLaunchKernelGGL(k0_prep, dim3(1), dim3(256), 0, stream, l2i, img_aug, conv_w, wsf);
    hipLaunchKernelGGL(k2_mfma, dim3(HW_/64, B_*NCAM_), dim3(256), 0, stream, feat, wbp, pf);
    hipLaunchKernelGGL(k3_gather, dim3(625, B_), dim3(320), 0, stream, wsf, lidar_aug, points, pf, conv_b, ybf, part);
    hipLaunchKernelGGL(k4_final, dim3(OUTC_), dim3(256), 0, stream, part, gamma, beta, wsf);
    hipLaunchKernelGGL(k5_norm, dim3((B_*OUTC_*NPOS_/8)/256 + 1, 1), dim3(256), 0, stream, (const u32*)ybf, wsf, out);
}